// Round 8
// baseline (330.507 us; speedup 1.0000x reference)
//
#include <hip/hip_runtime.h>
#include <hip/hip_bf16.h>

#define EMBED 1024
#define HEADS 16
#define HD    64
#define NB    4
#define SEQ   2048

typedef __bf16 bf16x2 __attribute__((ext_vector_type(2)));
typedef __bf16 bf16x8 __attribute__((ext_vector_type(8)));
typedef float  f32x4  __attribute__((ext_vector_type(4)));
typedef float  f32x16 __attribute__((ext_vector_type(16)));
typedef unsigned uint2v __attribute__((ext_vector_type(2)));

__device__ __forceinline__ unsigned short f2bf(float f) {
    union { float f; unsigned u; } v; v.f = f;
    unsigned r = v.u + 0x7fffu + ((v.u >> 16) & 1u);   // RNE, inputs finite
    return (unsigned short)(r >> 16);
}
// packed 2xf32 -> bf16x2 (low=a, high=b)
__device__ __forceinline__ unsigned pack2(float a, float b) {
#if __has_builtin(__builtin_amdgcn_cvt_pk_bf16_f32)
    union { bf16x2 v; unsigned u; } c;
    c.v = __builtin_amdgcn_cvt_pk_bf16_f32(a, b);
    return c.u;
#else
    return (unsigned)f2bf(a) | ((unsigned)f2bf(b) << 16);
#endif
}

// ---------------------------------------------------------------- Wo -> bf16
__global__ __launch_bounds__(256) void cvt_kernel(const float* __restrict__ src,
                                                  unsigned* __restrict__ dst) {
    int i = blockIdx.x * 256 + threadIdx.x;
    float4 v = ((const float4*)src)[i];
    uint2 o;
    o.x = pack2(v.x, v.y);
    o.y = pack2(v.z, v.w);
    ((uint2*)dst)[i] = o;
}

// ------------------------------------------------------- Q/K/V projections
// 256 s-rows per block. p=0: query@Wq^T (scale log2(e)/32 folded) -> Qp [h][s][d]
// p=1: keys@Wk^T -> Kp [h][s][d]   p=2: values@Wv^T -> Vt [h][d][s]
__global__ __launch_bounds__(256) void proj_kernel(
    const float* __restrict__ xq, const float* __restrict__ xk, const float* __restrict__ xv,
    const float* __restrict__ Wq, const float* __restrict__ Wk, const float* __restrict__ Wv,
    unsigned short* __restrict__ Qp, unsigned short* __restrict__ Kp, unsigned short* __restrict__ Vt)
{
    __shared__ __align__(16) unsigned short Wl[64 * 72];
    __shared__ __align__(16) unsigned short Xl[256 * 72];

    int bx = blockIdx.x;                  // 1536 = 3 * 512
    int p  = bx >> 9;
    int r  = bx & 511;
    int st = r & 7, h = (r >> 3) & 15, n = r >> 7;
    int s0 = st * 256;

    const float* x = (p == 0) ? xq : (p == 1) ? xk : xv;
    const float* W = (p == 0) ? Wq : (p == 1) ? Wk : Wv;
    const float sc = (p == 0) ? 0.045084220027780106f : 1.0f;  // log2(e)/32

    int tid = threadIdx.x;

    for (int i = 0; i < 4; ++i) {
        int idx = tid + i * 256;
        int row = idx >> 4, c4 = idx & 15;
        float4 wv = ((const float4*)W)[row * 16 + c4];
        uint2 pw;
        pw.x = pack2(wv.x, wv.y);
        pw.y = pack2(wv.z, wv.w);
        *(uint2*)&Wl[row * 72 + c4 * 4] = pw;
    }
    const float* xbase = x + (size_t)(n * SEQ + s0) * EMBED + h * HD;
    for (int i = 0; i < 16; ++i) {
        int idx = tid + i * 256;
        int row = idx >> 4, c4 = idx & 15;
        float4 v = *(const float4*)(xbase + (size_t)row * EMBED + c4 * 4);
        uint2 px;
        px.x = pack2(v.x, v.y);
        px.y = pack2(v.z, v.w);
        *(uint2*)&Xl[row * 72 + c4 * 4] = px;
    }
    __syncthreads();

    int w = tid >> 6, lane = tid & 63, ln = lane & 15, qd = lane >> 4;

    bf16x8 a[4][2], b[4][2];
#pragma unroll
    for (int mt = 0; mt < 4; ++mt)
#pragma unroll
        for (int kt = 0; kt < 2; ++kt)
            a[mt][kt] = *(const bf16x8*)&Xl[(w * 64 + mt * 16 + ln) * 72 + kt * 32 + qd * 8];
#pragma unroll
    for (int i = 0; i < 4; ++i)
#pragma unroll
        for (int kt = 0; kt < 2; ++kt)
            b[i][kt] = *(const bf16x8*)&Wl[(i * 16 + ln) * 72 + kt * 32 + qd * 8];

    f32x4 acc[4][4];
    const f32x4 fz = {0.f, 0.f, 0.f, 0.f};
#pragma unroll
    for (int i = 0; i < 4; ++i)
#pragma unroll
        for (int j = 0; j < 4; ++j) acc[i][j] = fz;

    if (p < 2) {
#pragma unroll
        for (int i = 0; i < 4; ++i)
#pragma unroll
            for (int j = 0; j < 4; ++j) {
                acc[i][j] = __builtin_amdgcn_mfma_f32_16x16x32_bf16(b[i][0], a[j][0], acc[i][j], 0, 0, 0);
                acc[i][j] = __builtin_amdgcn_mfma_f32_16x16x32_bf16(b[i][1], a[j][1], acc[i][j], 0, 0, 0);
            }
#pragma unroll
        for (int i = 0; i < 4; ++i)
#pragma unroll
            for (int j = 0; j < 4; ++j) {
                uint2 pk;
                pk.x = pack2(acc[i][j][0] * sc, acc[i][j][1] * sc);
                pk.y = pack2(acc[i][j][2] * sc, acc[i][j][3] * sc);
                *(uint2*)&Xl[(w * 64 + j * 16 + ln) * 72 + i * 16 + qd * 4] = pk;
            }
        __syncthreads();
        unsigned short* outp = (p == 0 ? Qp : Kp) + (size_t)(n * HEADS + h) * SEQ * HD + (size_t)s0 * HD;
        for (int i = 0; i < 8; ++i) {
            int idx = tid + i * 256;
            int row = idx >> 3, ch = idx & 7;
            *(uint4*)(outp + (size_t)row * HD + ch * 8) = *(const uint4*)&Xl[row * 72 + ch * 8];
        }
    } else {
#pragma unroll
        for (int mt = 0; mt < 4; ++mt)
#pragma unroll
            for (int i = 0; i < 4; ++i) {
                acc[mt][i] = __builtin_amdgcn_mfma_f32_16x16x32_bf16(a[mt][0], b[i][0], acc[mt][i], 0, 0, 0);
                acc[mt][i] = __builtin_amdgcn_mfma_f32_16x16x32_bf16(a[mt][1], b[i][1], acc[mt][i], 0, 0, 0);
            }
        __syncthreads();
#pragma unroll
        for (int mt = 0; mt < 4; ++mt)
#pragma unroll
            for (int i = 0; i < 4; ++i) {
                uint2 pk;
                pk.x = pack2(acc[mt][i][0], acc[mt][i][1]);
                pk.y = pack2(acc[mt][i][2], acc[mt][i][3]);
                *(uint2*)&Xl[(i * 16 + ln) * 264 + w * 64 + mt * 16 + qd * 4] = pk;
            }
        __syncthreads();
        unsigned short* outp = Vt + (size_t)(n * HEADS + h) * HD * SEQ + s0;
        for (int i = 0; i < 8; ++i) {
            int idx = tid + i * 256;
            int row = idx >> 5, ch = idx & 31;
            *(uint4*)(outp + (size_t)row * SEQ + ch * 8) = *(const uint4*)&Xl[row * 264 + ch * 8];
        }
    }
}

// ------------------------------------------------------------ flash attention
// 32x32x16 MFMAs. S^T = K Q^T (C: col=q, row=key). P stays in registers; the
// PV B-fragment is assembled with v_permlane32_swap (gfx950): with
// r=swap(P[b+0],P[b+2]), rr=swap(P[b+1],P[b+3]) the frag is {r.x,rr.x,r.y,rr.y}
// exactly — no selects, no DS ops. shfl_xor fallback if builtin missing.
__global__ __launch_bounds__(512, 4) void attn_kernel(
    const unsigned short* __restrict__ Qp, const unsigned short* __restrict__ Kp,
    const unsigned short* __restrict__ Vt, unsigned short* __restrict__ Xattn)
{
    __shared__ __align__(16) unsigned short SMEM[18432];   // 36,864 B
    unsigned short* Kl = SMEM;           // [2][64*72]  (key, d)
    unsigned short* Vl = SMEM + 9216;    // [2][64*72]  (d, key)

    int bx = blockIdx.x;                 // 512 blocks: head*8 + qtile
    int head = bx >> 3, qt = bx & 7;
    int n = head >> 4, h16 = head & 15;
    int q0 = qt * 256;

    int tid = threadIdx.x;
    int w = tid >> 6, lane = tid & 63;
    int qc = lane & 31, hh = lane >> 5;

    const unsigned short* Qb = Qp + (size_t)head * SEQ * HD;
    const unsigned short* Kb = Kp + (size_t)head * SEQ * HD;
    const unsigned short* Vb = Vt + (size_t)head * HD * SEQ;

    // Q as B-operand (32x32x16): lane n=q, k(d) = kk*16 + hh*8 + j
    bf16x8 qb[4];
    {
        int qrow = q0 + w * 32 + qc;
#pragma unroll
        for (int kk = 0; kk < 4; ++kk)
            qb[kk] = *(const bf16x8*)(Qb + (size_t)qrow * HD + kk * 16 + hh * 8);
    }

    f32x16 ot0, ot1;
#pragma unroll
    for (int i = 0; i < 16; ++i) { ot0[i] = 0.f; ot1[i] = 0.f; }
    float ls[4] = {0.f, 0.f, 0.f, 0.f};     // 4-way partials, independent chains

    int srow = tid >> 3, sch = tid & 7;      // staging: 64 rows x 8 chunks

    // prologue: chunk 0 -> regs -> buf0 ; chunk 1 -> regs
    uint4 rK, rV;
    rK = *(const uint4*)(Kb + (size_t)srow * HD + sch * 8);
    rV = *(const uint4*)(Vb + (size_t)srow * SEQ + 0 + sch * 8);
    *(uint4*)&Kl[srow * 72 + sch * 8] = rK;
    *(uint4*)&Vl[srow * 72 + sch * 8] = rV;
    rK = *(const uint4*)(Kb + (size_t)(64 + srow) * HD + sch * 8);
    rV = *(const uint4*)(Vb + (size_t)srow * SEQ + 64 + sch * 8);

    for (int kc = 0; kc < SEQ; kc += 64) {
        int cur = (kc >> 6) & 1, nxt = cur ^ 1;
        int curo = cur * 4608;
        __syncthreads();   // chunk kc staged+visible; prior reads of buf[nxt] done

        if (kc + 64 < SEQ) {
            *(uint4*)&Kl[nxt * 4608 + srow * 72 + sch * 8] = rK;
            *(uint4*)&Vl[nxt * 4608 + srow * 72 + sch * 8] = rV;
            int kn = kc + 128 <= SEQ - 64 ? kc + 128 : SEQ - 64;
            rK = *(const uint4*)(Kb + (size_t)(kn + srow) * HD + sch * 8);
            rV = *(const uint4*)(Vb + (size_t)srow * SEQ + kn + sch * 8);
        }

        // ---- S^T = K Q^T (32x32 tiles), exp2, pack to bf16 pairs in regs
        unsigned pk[2][8];
#pragma unroll
        for (int kt = 0; kt < 2; ++kt) {
            f32x16 c;
#pragma unroll
            for (int i = 0; i < 16; ++i) c[i] = 0.f;
#pragma unroll
            for (int kk = 0; kk < 4; ++kk) {
                bf16x8 ka = *(const bf16x8*)&Kl[curo + (kt * 32 + qc) * 72 + kk * 16 + hh * 8];
                c = __builtin_amdgcn_mfma_f32_32x32x16_bf16(ka, qb[kk], c, 0, 0, 0);
            }
#pragma unroll
            for (int i = 0; i < 8; ++i) {
                float p0 = __builtin_amdgcn_exp2f(c[2 * i]);
                float p1 = __builtin_amdgcn_exp2f(c[2 * i + 1]);
                ls[i & 3] += p0 + p1;
                pk[kt][i] = pack2(p0, p1);
            }
        }

        // ---- O^T += V^T P^T : assemble B-frag per 16-key block
#pragma unroll
        for (int g = 0; g < 4; ++g) {
            const unsigned* P = pk[g >> 1];
            int base = (g & 1) * 4;
            union { unsigned u[4]; bf16x8 v; } bb;
#if __has_builtin(__builtin_amdgcn_permlane32_swap)
            uint2v r  = __builtin_amdgcn_permlane32_swap(P[base + 0], P[base + 2], false, false);
            uint2v rr = __builtin_amdgcn_permlane32_swap(P[base + 1], P[base + 3], false, false);
            bb.u[0] = r.x;
            bb.u[1] = rr.x;
            bb.u[2] = r.y;
            bb.u[3] = rr.y;
#else
            unsigned s0 = hh ? P[base + 0] : P[base + 2];
            unsigned s1 = hh ? P[base + 1] : P[base + 3];
            unsigned r0 = (unsigned)__shfl_xor((int)s0, 32);
            unsigned r1 = (unsigned)__shfl_xor((int)s1, 32);
            bb.u[0] = hh ? r0 : P[base + 0];
            bb.u[1] = hh ? r1 : P[base + 1];
            bb.u[2] = hh ? P[base + 2] : r0;
            bb.u[3] = hh ? P[base + 3] : r1;
#endif
            bf16x8 va0 = *(const bf16x8*)&Vl[curo + qc * 72 + g * 16 + hh * 8];
            bf16x8 va1 = *(const bf16x8*)&Vl[curo + (32 + qc) * 72 + g * 16 + hh * 8];
            ot0 = __builtin_amdgcn_mfma_f32_32x32x16_bf16(va0, bb.v, ot0, 0, 0, 0);
            ot1 = __builtin_amdgcn_mfma_f32_32x32x16_bf16(va1, bb.v, ot1, 0, 0, 0);
        }
    }

    // ---- finish l (combine partials, then the xor-32 partner half)
    float lsum = (ls[0] + ls[1]) + (ls[2] + ls[3]);
    lsum += __shfl_xor(lsum, 32);
    float inv = 1.0f / lsum;

    // ---- stage O [q][d] into SMEM (reuses K/V space), coalesced store
    __syncthreads();
    int qlocal = w * 32 + qc;
#pragma unroll
    for (int dt = 0; dt < 2; ++dt) {
        const f32x16& o = dt ? ot1 : ot0;
#pragma unroll
        for (int g = 0; g < 4; ++g) {
            uint2 p;
            p.x = pack2(o[4 * g + 0] * inv, o[4 * g + 1] * inv);
            p.y = pack2(o[4 * g + 2] * inv, o[4 * g + 3] * inv);
            *(uint2*)&SMEM[qlocal * 72 + dt * 32 + g * 8 + hh * 4] = p;
        }
    }
    __syncthreads();
    unsigned short* ob = Xattn + (size_t)(n * SEQ + q0) * EMBED + h16 * HD;
#pragma unroll
    for (int i = 0; i < 4; ++i) {
        int idx = tid + i * 512;                 // 256 rows x 8 chunks
        int row = idx >> 3, ch = idx & 7;
        *(uint4*)(ob + (size_t)row * EMBED + ch * 8) = *(const uint4*)&SMEM[row * 72 + ch * 8];
    }
}

// ----------------------------------------------------- out = Xattn@Wo^T + bo
// Reg-prefetch pipeline, SINGLE 36 KB LDS buffer (4 blocks/CU): loads for
// slab k+1 issue right after the write-barrier and complete under slab k's
// MFMA compute — no exposed global latency, no LDS doubling.
__global__ __launch_bounds__(256) void outproj_kernel(
    const unsigned short* __restrict__ X, const unsigned short* __restrict__ Wb,
    const float* __restrict__ bo, float* __restrict__ out)
{
    __shared__ __align__(16) unsigned short Al[128 * 72];
    __shared__ __align__(16) unsigned short Bl[128 * 72];

    int bx = blockIdx.x;
    int cm = bx >> 3, cn = bx & 7;
    int m0 = cm * 128, c0 = cn * 128;
    int tid = threadIdx.x;
    int w = tid >> 6, lane = tid & 63, ln = lane & 15, qd = lane >> 4;
    int rh = (w & 1) * 64, chh = (w >> 1) * 64;

    f32x4 acc[4][4];
    const f32x4 fz = {0.f, 0.f, 0.f, 0.f};
#pragma unroll
    for (int mt = 0; mt < 4; ++mt)
#pragma unroll
        for (int nt = 0; nt < 4; ++nt) acc[mt][nt] = fz;

    int srow = tid >> 1, sch = tid & 1;   // 128 rows x 2 lanes; 4 uint4 chunks each

    uint4 rA[4], rB[4];
#pragma unroll
    for (int i = 0; i < 4; ++i) {
        rA[i] = *(const uint4*)(X  + (size_t)(m0 + srow) * EMBED + (sch * 4 + i) * 8);
        rB[i] = *(const uint4*)(Wb + (size_t)(c0 + srow) * EMBED + (sch * 4 + i) * 8);
    }

    for (int k0 = 0; k0 < EMBED; k0 += 64) {
        // write current slab (regs) into LDS; prior compute's reads are done
        // (loop-end barrier), loads completed during prior compute
#pragma unroll
        for (int i = 0; i < 4; ++i) {
            *(uint4*)&Al[srow * 72 + (sch * 4 + i) * 8] = rA[i];
            *(uint4*)&Bl[srow * 72 + (sch * 4 + i) * 8] = rB[i];
        }
        __syncthreads();

        if (k0 + 64 < EMBED) {
            int kn = k0 + 64;
#pragma unroll
            for (int i = 0; i < 4; ++i) {
                rA[i] = *(const uint4*)(X  + (size_t)(m0 + srow) * EMBED + kn + (sch * 4 + i) * 8);
                rB[i] = *(const uint4*)(Wb + (size_t)(c0 + srow) * EMBED + kn + (sch * 4 + i) * 8);
            }
        }

        bf16x8 af[4][2], bf_[4][2];
#pragma unroll
        for (int mt = 0; mt < 4; ++mt)
#pragma unroll
            for (int kt = 0; kt < 2; ++kt)
                af[mt][kt] = *(const bf16x8*)&Al[(rh + mt * 16 + ln) * 72 + kt * 32 + qd * 8];
#pragma unroll
        for (int nt = 0; nt < 4; ++nt)
#pragma unroll
            for (int kt = 0; kt < 2; ++kt)
                bf_[nt][kt] = *(const bf16x8*)&Bl[(chh + nt * 16 + ln) * 72 + kt * 32 + qd * 8];
#pragma unroll
        for (int mt = 0; mt < 4; ++mt)
#pragma unroll
            for (int nt = 0; nt < 4; ++nt) {
                acc[mt][nt] = __builtin_amdgcn_mfma_f32_16x16x32_bf16(af[mt][0], bf_[nt][0], acc[mt][nt], 0, 0, 0);
                acc[mt][nt] = __builtin_amdgcn_mfma_f32_16x16x32_bf16(af[mt][1], bf_[nt][1], acc[mt][nt], 0, 0, 0);
            }
        __syncthreads();   // all LDS reads done before next slab's writes
    }

#pragma unroll
    for (int nt = 0; nt < 4; ++nt) {
        int col = c0 + chh + nt * 16 + ln;
        float bias = bo[col];
#pragma unroll
        for (int mt = 0; mt < 4; ++mt) {
            int row = m0 + rh + mt * 16 + qd * 4;
#pragma unroll
            for (int rg = 0; rg < 4; ++rg)
                out[(size_t)(row + rg) * EMBED + col] = acc[mt][nt][rg] + bias;
        }
    }
}

// --------------------------------------------------------------------- launch
extern "C" void kernel_launch(void* const* d_in, const int* in_sizes, int n_in,
                              void* d_out, int out_size, void* d_ws, size_t ws_size,
                              hipStream_t stream) {
    const float* values = (const float*)d_in[0];
    const float* keys   = (const float*)d_in[1];
    const float* query  = (const float*)d_in[2];
    const float* Wv     = (const float*)d_in[3];
    const float* Wk     = (const float*)d_in[4];
    const float* Wq     = (const float*)d_in[5];
    const float* Wo     = (const float*)d_in[6];
    const float* bo     = (const float*)d_in[7];
    float* out = (float*)d_out;

    unsigned short* ws = (unsigned short*)d_ws;
    const size_t HSZ = (size_t)NB * HEADS * SEQ * HD;   // 8388608 elems
    unsigned short* Qp = ws;
    unsigned short* Kp = Qp + HSZ;
    unsigned short* Vt = Kp + HSZ;
    unsigned short* Xa = Vt + HSZ;
    unsigned short* Wb = Xa + HSZ;                       // 1024*1024 elems

    cvt_kernel<<<1024, 256, 0, stream>>>(Wo, (unsigned*)Wb);
    proj_kernel<<<1536, 256, 0, stream>>>(query, keys, values, Wq, Wk, Wv, Qp, Kp, Vt);
    attn_kernel<<<512, 512, 0, stream>>>(Qp, Kp, Vt, Xa);
    outproj_kernel<<<512, 256, 0, stream>>>(Xa, Wb, bo, out);
}

// Round 9
// 264.581 us; speedup vs baseline: 1.2492x; 1.2492x over previous
//
#include <hip/hip_runtime.h>
#include <hip/hip_bf16.h>

#define EMBED 1024
#define HEADS 16
#define HD    64
#define NB    4
#define SEQ   2048

typedef __bf16 bf16x2 __attribute__((ext_vector_type(2)));
typedef __bf16 bf16x8 __attribute__((ext_vector_type(8)));
typedef float  f32x4  __attribute__((ext_vector_type(4)));
typedef float  f32x16 __attribute__((ext_vector_type(16)));
typedef unsigned uint2v __attribute__((ext_vector_type(2)));

__device__ __forceinline__ unsigned short f2bf(float f) {
    union { float f; unsigned u; } v; v.f = f;
    unsigned r = v.u + 0x7fffu + ((v.u >> 16) & 1u);   // RNE, inputs finite
    return (unsigned short)(r >> 16);
}
// packed 2xf32 -> bf16x2 (low=a, high=b)
__device__ __forceinline__ unsigned pack2(float a, float b) {
#if __has_builtin(__builtin_amdgcn_cvt_pk_bf16_f32)
    union { bf16x2 v; unsigned u; } c;
    c.v = __builtin_amdgcn_cvt_pk_bf16_f32(a, b);
    return c.u;
#else
    return (unsigned)f2bf(a) | ((unsigned)f2bf(b) << 16);
#endif
}

// ---------------------------------------------------------------- Wo -> bf16
__global__ __launch_bounds__(256) void cvt_kernel(const float* __restrict__ src,
                                                  unsigned* __restrict__ dst) {
    int i = blockIdx.x * 256 + threadIdx.x;
    float4 v = ((const float4*)src)[i];
    uint2 o;
    o.x = pack2(v.x, v.y);
    o.y = pack2(v.z, v.w);
    ((uint2*)dst)[i] = o;
}

// ------------------------------------------------------- Q/K/V projections
// 256 s-rows per block. p=0: query@Wq^T (scale log2(e)/32 folded) -> Qp [h][s][d]
// p=1: keys@Wk^T -> Kp [h][s][d]   p=2: values@Wv^T -> Vt [h][d][s]
__global__ __launch_bounds__(256) void proj_kernel(
    const float* __restrict__ xq, const float* __restrict__ xk, const float* __restrict__ xv,
    const float* __restrict__ Wq, const float* __restrict__ Wk, const float* __restrict__ Wv,
    unsigned short* __restrict__ Qp, unsigned short* __restrict__ Kp, unsigned short* __restrict__ Vt)
{
    __shared__ __align__(16) unsigned short Wl[64 * 72];
    __shared__ __align__(16) unsigned short Xl[256 * 72];

    int bx = blockIdx.x;                  // 1536 = 3 * 512
    int p  = bx >> 9;
    int r  = bx & 511;
    int st = r & 7, h = (r >> 3) & 15, n = r >> 7;
    int s0 = st * 256;

    const float* x = (p == 0) ? xq : (p == 1) ? xk : xv;
    const float* W = (p == 0) ? Wq : (p == 1) ? Wk : Wv;
    const float sc = (p == 0) ? 0.045084220027780106f : 1.0f;  // log2(e)/32

    int tid = threadIdx.x;

    for (int i = 0; i < 4; ++i) {
        int idx = tid + i * 256;
        int row = idx >> 4, c4 = idx & 15;
        float4 wv = ((const float4*)W)[row * 16 + c4];
        uint2 pw;
        pw.x = pack2(wv.x, wv.y);
        pw.y = pack2(wv.z, wv.w);
        *(uint2*)&Wl[row * 72 + c4 * 4] = pw;
    }
    const float* xbase = x + (size_t)(n * SEQ + s0) * EMBED + h * HD;
    for (int i = 0; i < 16; ++i) {
        int idx = tid + i * 256;
        int row = idx >> 4, c4 = idx & 15;
        float4 v = *(const float4*)(xbase + (size_t)row * EMBED + c4 * 4);
        uint2 px;
        px.x = pack2(v.x, v.y);
        px.y = pack2(v.z, v.w);
        *(uint2*)&Xl[row * 72 + c4 * 4] = px;
    }
    __syncthreads();

    int w = tid >> 6, lane = tid & 63, ln = lane & 15, qd = lane >> 4;

    bf16x8 a[4][2], b[4][2];
#pragma unroll
    for (int mt = 0; mt < 4; ++mt)
#pragma unroll
        for (int kt = 0; kt < 2; ++kt)
            a[mt][kt] = *(const bf16x8*)&Xl[(w * 64 + mt * 16 + ln) * 72 + kt * 32 + qd * 8];
#pragma unroll
    for (int i = 0; i < 4; ++i)
#pragma unroll
        for (int kt = 0; kt < 2; ++kt)
            b[i][kt] = *(const bf16x8*)&Wl[(i * 16 + ln) * 72 + kt * 32 + qd * 8];

    f32x4 acc[4][4];
    const f32x4 fz = {0.f, 0.f, 0.f, 0.f};
#pragma unroll
    for (int i = 0; i < 4; ++i)
#pragma unroll
        for (int j = 0; j < 4; ++j) acc[i][j] = fz;

    if (p < 2) {
#pragma unroll
        for (int i = 0; i < 4; ++i)
#pragma unroll
            for (int j = 0; j < 4; ++j) {
                acc[i][j] = __builtin_amdgcn_mfma_f32_16x16x32_bf16(b[i][0], a[j][0], acc[i][j], 0, 0, 0);
                acc[i][j] = __builtin_amdgcn_mfma_f32_16x16x32_bf16(b[i][1], a[j][1], acc[i][j], 0, 0, 0);
            }
#pragma unroll
        for (int i = 0; i < 4; ++i)
#pragma unroll
            for (int j = 0; j < 4; ++j) {
                uint2 pk;
                pk.x = pack2(acc[i][j][0] * sc, acc[i][j][1] * sc);
                pk.y = pack2(acc[i][j][2] * sc, acc[i][j][3] * sc);
                *(uint2*)&Xl[(w * 64 + j * 16 + ln) * 72 + i * 16 + qd * 4] = pk;
            }
        __syncthreads();
        unsigned short* outp = (p == 0 ? Qp : Kp) + (size_t)(n * HEADS + h) * SEQ * HD + (size_t)s0 * HD;
        for (int i = 0; i < 8; ++i) {
            int idx = tid + i * 256;
            int row = idx >> 3, ch = idx & 7;
            *(uint4*)(outp + (size_t)row * HD + ch * 8) = *(const uint4*)&Xl[row * 72 + ch * 8];
        }
    } else {
#pragma unroll
        for (int mt = 0; mt < 4; ++mt)
#pragma unroll
            for (int i = 0; i < 4; ++i) {
                acc[mt][i] = __builtin_amdgcn_mfma_f32_16x16x32_bf16(a[mt][0], b[i][0], acc[mt][i], 0, 0, 0);
                acc[mt][i] = __builtin_amdgcn_mfma_f32_16x16x32_bf16(a[mt][1], b[i][1], acc[mt][i], 0, 0, 0);
            }
        __syncthreads();
#pragma unroll
        for (int mt = 0; mt < 4; ++mt)
#pragma unroll
            for (int i = 0; i < 4; ++i) {
                uint2 pk;
                pk.x = pack2(acc[mt][i][0], acc[mt][i][1]);
                pk.y = pack2(acc[mt][i][2], acc[mt][i][3]);
                *(uint2*)&Xl[(i * 16 + ln) * 264 + w * 64 + mt * 16 + qd * 4] = pk;
            }
        __syncthreads();
        unsigned short* outp = Vt + (size_t)(n * HEADS + h) * HD * SEQ + s0;
        for (int i = 0; i < 8; ++i) {
            int idx = tid + i * 256;
            int row = idx >> 5, ch = idx & 31;
            *(uint4*)(outp + (size_t)row * SEQ + ch * 8) = *(const uint4*)&Xl[row * 264 + ch * 8];
        }
    }
}

// ------------------------------------------------------------ flash attention
// 32x32x16 MFMAs. S^T = K Q^T (C: col=q, row=key). P stays in registers; the
// PV B-fragment is assembled with v_permlane32_swap (shfl_xor fallback).
__global__ __launch_bounds__(512, 4) void attn_kernel(
    const unsigned short* __restrict__ Qp, const unsigned short* __restrict__ Kp,
    const unsigned short* __restrict__ Vt, unsigned short* __restrict__ Xattn)
{
    __shared__ __align__(16) unsigned short SMEM[18432];   // 36,864 B
    unsigned short* Kl = SMEM;           // [2][64*72]  (key, d)
    unsigned short* Vl = SMEM + 9216;    // [2][64*72]  (d, key)

    int bx = blockIdx.x;                 // 512 blocks: head*8 + qtile
    int head = bx >> 3, qt = bx & 7;
    int n = head >> 4, h16 = head & 15;
    int q0 = qt * 256;

    int tid = threadIdx.x;
    int w = tid >> 6, lane = tid & 63;
    int qc = lane & 31, hh = lane >> 5;

    const unsigned short* Qb = Qp + (size_t)head * SEQ * HD;
    const unsigned short* Kb = Kp + (size_t)head * SEQ * HD;
    const unsigned short* Vb = Vt + (size_t)head * HD * SEQ;

    // Q as B-operand (32x32x16): lane n=q, k(d) = kk*16 + hh*8 + j
    bf16x8 qb[4];
    {
        int qrow = q0 + w * 32 + qc;
#pragma unroll
        for (int kk = 0; kk < 4; ++kk)
            qb[kk] = *(const bf16x8*)(Qb + (size_t)qrow * HD + kk * 16 + hh * 8);
    }

    f32x16 ot0, ot1;
#pragma unroll
    for (int i = 0; i < 16; ++i) { ot0[i] = 0.f; ot1[i] = 0.f; }
    float ls[4] = {0.f, 0.f, 0.f, 0.f};     // 4-way partials, independent chains

    int srow = tid >> 3, sch = tid & 7;      // staging: 64 rows x 8 chunks

    // prologue: chunk 0 -> regs -> buf0 ; chunk 1 -> regs
    uint4 rK, rV;
    rK = *(const uint4*)(Kb + (size_t)srow * HD + sch * 8);
    rV = *(const uint4*)(Vb + (size_t)srow * SEQ + 0 + sch * 8);
    *(uint4*)&Kl[srow * 72 + sch * 8] = rK;
    *(uint4*)&Vl[srow * 72 + sch * 8] = rV;
    rK = *(const uint4*)(Kb + (size_t)(64 + srow) * HD + sch * 8);
    rV = *(const uint4*)(Vb + (size_t)srow * SEQ + 64 + sch * 8);

    for (int kc = 0; kc < SEQ; kc += 64) {
        int cur = (kc >> 6) & 1, nxt = cur ^ 1;
        int curo = cur * 4608;
        __syncthreads();   // chunk kc staged+visible; prior reads of buf[nxt] done

        if (kc + 64 < SEQ) {
            *(uint4*)&Kl[nxt * 4608 + srow * 72 + sch * 8] = rK;
            *(uint4*)&Vl[nxt * 4608 + srow * 72 + sch * 8] = rV;
            int kn = kc + 128 <= SEQ - 64 ? kc + 128 : SEQ - 64;
            rK = *(const uint4*)(Kb + (size_t)(kn + srow) * HD + sch * 8);
            rV = *(const uint4*)(Vb + (size_t)srow * SEQ + kn + sch * 8);
        }

        // ---- S^T = K Q^T (32x32 tiles), exp2, pack to bf16 pairs in regs
        unsigned pk[2][8];
#pragma unroll
        for (int kt = 0; kt < 2; ++kt) {
            f32x16 c;
#pragma unroll
            for (int i = 0; i < 16; ++i) c[i] = 0.f;
#pragma unroll
            for (int kk = 0; kk < 4; ++kk) {
                bf16x8 ka = *(const bf16x8*)&Kl[curo + (kt * 32 + qc) * 72 + kk * 16 + hh * 8];
                c = __builtin_amdgcn_mfma_f32_32x32x16_bf16(ka, qb[kk], c, 0, 0, 0);
            }
#pragma unroll
            for (int i = 0; i < 8; ++i) {
                float p0 = __builtin_amdgcn_exp2f(c[2 * i]);
                float p1 = __builtin_amdgcn_exp2f(c[2 * i + 1]);
                ls[i & 3] += p0 + p1;
                pk[kt][i] = pack2(p0, p1);
            }
        }

        // ---- O^T += V^T P^T : assemble B-frag per 16-key block
#pragma unroll
        for (int g = 0; g < 4; ++g) {
            const unsigned* P = pk[g >> 1];
            int base = (g & 1) * 4;
            union { unsigned u[4]; bf16x8 v; } bb;
#if __has_builtin(__builtin_amdgcn_permlane32_swap)
            uint2v r  = __builtin_amdgcn_permlane32_swap(P[base + 0], P[base + 2], false, false);
            uint2v rr = __builtin_amdgcn_permlane32_swap(P[base + 1], P[base + 3], false, false);
            bb.u[0] = r.x;
            bb.u[1] = rr.x;
            bb.u[2] = r.y;
            bb.u[3] = rr.y;
#else
            unsigned s0 = hh ? P[base + 0] : P[base + 2];
            unsigned s1 = hh ? P[base + 1] : P[base + 3];
            unsigned r0 = (unsigned)__shfl_xor((int)s0, 32);
            unsigned r1 = (unsigned)__shfl_xor((int)s1, 32);
            bb.u[0] = hh ? r0 : P[base + 0];
            bb.u[1] = hh ? r1 : P[base + 1];
            bb.u[2] = hh ? P[base + 2] : r0;
            bb.u[3] = hh ? P[base + 3] : r1;
#endif
            bf16x8 va0 = *(const bf16x8*)&Vl[curo + qc * 72 + g * 16 + hh * 8];
            bf16x8 va1 = *(const bf16x8*)&Vl[curo + (32 + qc) * 72 + g * 16 + hh * 8];
            ot0 = __builtin_amdgcn_mfma_f32_32x32x16_bf16(va0, bb.v, ot0, 0, 0, 0);
            ot1 = __builtin_amdgcn_mfma_f32_32x32x16_bf16(va1, bb.v, ot1, 0, 0, 0);
        }
    }

    // ---- finish l (combine partials, then the xor-32 partner half)
    float lsum = (ls[0] + ls[1]) + (ls[2] + ls[3]);
    lsum += __shfl_xor(lsum, 32);
    float inv = 1.0f / lsum;

    // ---- stage O [q][d] into SMEM (reuses K/V space), coalesced store
    __syncthreads();
    int qlocal = w * 32 + qc;
#pragma unroll
    for (int dt = 0; dt < 2; ++dt) {
        const f32x16& o = dt ? ot1 : ot0;
#pragma unroll
        for (int g = 0; g < 4; ++g) {
            uint2 p;
            p.x = pack2(o[4 * g + 0] * inv, o[4 * g + 1] * inv);
            p.y = pack2(o[4 * g + 2] * inv, o[4 * g + 3] * inv);
            *(uint2*)&SMEM[qlocal * 72 + dt * 32 + g * 8 + hh * 4] = p;
        }
    }
    __syncthreads();
    unsigned short* ob = Xattn + (size_t)(n * SEQ + q0) * EMBED + h16 * HD;
#pragma unroll
    for (int i = 0; i < 4; ++i) {
        int idx = tid + i * 512;                 // 256 rows x 8 chunks
        int row = idx >> 3, ch = idx & 7;
        *(uint4*)(ob + (size_t)row * EMBED + ch * 8) = *(const uint4*)&SMEM[row * 72 + ch * 8];
    }
}

// ----------------------------------------------------- out = Xattn@Wo^T + bo
// 64x128 tiles -> grid 1024 -> 4 blocks/CU (16 waves/CU): cross-block TLP
// hides the synchronous K-loop's staging latency. LDS 27.6 KB.
__global__ __launch_bounds__(256, 4) void outproj_kernel(
    const unsigned short* __restrict__ X, const unsigned short* __restrict__ Wb,
    const float* __restrict__ bo, float* __restrict__ out)
{
    __shared__ __align__(16) unsigned short Al[64 * 72];
    __shared__ __align__(16) unsigned short Bl[128 * 72];

    int bx = blockIdx.x;                 // 1024 = 128 row-tiles x 8 col-tiles
    int cm = bx >> 3, cn = bx & 7;
    int m0 = cm * 64, c0 = cn * 128;
    int tid = threadIdx.x;
    int w = tid >> 6, lane = tid & 63, ln = lane & 15, qd = lane >> 4;
    int chw = w * 32;                    // wave's 32-col slice

    f32x4 acc[4][2];
    const f32x4 fz = {0.f, 0.f, 0.f, 0.f};
#pragma unroll
    for (int mt = 0; mt < 4; ++mt)
#pragma unroll
        for (int nt = 0; nt < 2; ++nt) acc[mt][nt] = fz;

    for (int k0 = 0; k0 < EMBED; k0 += 64) {
        {
            int row = tid >> 3, ch = tid & 7;    // A: 64 rows x 8 chunks (first 512 thr-slots)
            if (tid < 512) {                      // always true (256 thr, 2 iters below)
            }
#pragma unroll
            for (int i = 0; i < 2; ++i) {
                int idx = tid + i * 256;          // 512 uint4
                int r2 = idx >> 3, c2 = idx & 7;
                uint4 av = *(const uint4*)(X + (size_t)(m0 + r2) * EMBED + k0 + c2 * 8);
                *(uint4*)&Al[r2 * 72 + c2 * 8] = av;
            }
#pragma unroll
            for (int i = 0; i < 4; ++i) {
                int idx = tid + i * 256;          // 1024 uint4
                int r2 = idx >> 3, c2 = idx & 7;
                uint4 bv = *(const uint4*)(Wb + (size_t)(c0 + r2) * EMBED + k0 + c2 * 8);
                *(uint4*)&Bl[r2 * 72 + c2 * 8] = bv;
            }
            (void)row; (void)ch;
        }
        __syncthreads();
        bf16x8 af[4][2], bf_[2][2];
#pragma unroll
        for (int mt = 0; mt < 4; ++mt)
#pragma unroll
            for (int kt = 0; kt < 2; ++kt)
                af[mt][kt] = *(const bf16x8*)&Al[(mt * 16 + ln) * 72 + kt * 32 + qd * 8];
#pragma unroll
        for (int nt = 0; nt < 2; ++nt)
#pragma unroll
            for (int kt = 0; kt < 2; ++kt)
                bf_[nt][kt] = *(const bf16x8*)&Bl[(chw + nt * 16 + ln) * 72 + kt * 32 + qd * 8];
#pragma unroll
        for (int mt = 0; mt < 4; ++mt)
#pragma unroll
            for (int nt = 0; nt < 2; ++nt) {
                acc[mt][nt] = __builtin_amdgcn_mfma_f32_16x16x32_bf16(af[mt][0], bf_[nt][0], acc[mt][nt], 0, 0, 0);
                acc[mt][nt] = __builtin_amdgcn_mfma_f32_16x16x32_bf16(af[mt][1], bf_[nt][1], acc[mt][nt], 0, 0, 0);
            }
        __syncthreads();
    }

#pragma unroll
    for (int nt = 0; nt < 2; ++nt) {
        int col = c0 + chw + nt * 16 + ln;
        float bias = bo[col];
#pragma unroll
        for (int mt = 0; mt < 4; ++mt) {
            int row = m0 + mt * 16 + qd * 4;
#pragma unroll
            for (int rg = 0; rg < 4; ++rg)
                out[(size_t)(row + rg) * EMBED + col] = acc[mt][nt][rg] + bias;
        }
    }
}

// --------------------------------------------------------------------- launch
extern "C" void kernel_launch(void* const* d_in, const int* in_sizes, int n_in,
                              void* d_out, int out_size, void* d_ws, size_t ws_size,
                              hipStream_t stream) {
    const float* values = (const float*)d_in[0];
    const float* keys   = (const float*)d_in[1];
    const float* query  = (const float*)d_in[2];
    const float* Wv     = (const float*)d_in[3];
    const float* Wk     = (const float*)d_in[4];
    const float* Wq     = (const float*)d_in[5];
    const float* Wo     = (const float*)d_in[6];
    const float* bo     = (const float*)d_in[7];
    float* out = (float*)d_out;

    unsigned short* ws = (unsigned short*)d_ws;
    const size_t HSZ = (size_t)NB * HEADS * SEQ * HD;   // 8388608 elems
    unsigned short* Qp = ws;
    unsigned short* Kp = Qp + HSZ;
    unsigned short* Vt = Kp + HSZ;
    unsigned short* Xa = Vt + HSZ;
    unsigned short* Wb = Xa + HSZ;                       // 1024*1024 elems

    cvt_kernel<<<1024, 256, 0, stream>>>(Wo, (unsigned*)Wb);
    proj_kernel<<<1536, 256, 0, stream>>>(query, keys, values, Wq, Wk, Wv, Qp, Kp, Vt);
    attn_kernel<<<512, 512, 0, stream>>>(Qp, Kp, Vt, Xa);
    outproj_kernel<<<1024, 256, 0, stream>>>(Xa, Wb, bo, out);
}